// Round 9
// baseline (14136.722 us; speedup 1.0000x reference)
//
#include <hip/hip_runtime.h>

typedef _Float16 f16;
typedef f16 h8v __attribute__((ext_vector_type(8)));
typedef f16 h4v __attribute__((ext_vector_type(4)));
typedef float f4v __attribute__((ext_vector_type(4)));

#define TT 200
#define NTHR 512
#define NWG 256

// ---- d_ws layout (f16-element offsets) ----
#define W0F   0          // w_hh0  frag [64 tiles][512 h8v]
#define W1IF  262144     // w_ih1
#define W1HF  524288     // w_hh1
#define OW1F  786432     // out_w1 frag [8 tiles]
#define EW2F  819200     // enc_w2 frag [16 tiles]
#define EW3F  884736     // enc_w3 frag [16 tiles]
#define HIWF  950272     // hinit_w frag [32 tiles]
#define CIWF  1081344    // cinit_w frag [32 tiles]
#define FRAG_TOTAL 1212416  // == CIWF + 131072; conv_w must cover ALL of it
#define H0F   1212416    // h0 state [2 parity][16 g][16 m][512][16] f16
#define H1F   5406720    // h1 state (same shape)
#define O1F   9601024    // o1 [16 g][8 tile][512][16] f16
#define DECF  10649600   // dec [16 g][2 parity][512][4] FLOAT (occupies 131072 f16 units)
#define FLGF  10780672   // int32 flags [16 g][8] at byte offset FLGF*2

// flag indices
#define FE1 0
#define FE2 1
#define FE3 2
#define FDEC 3
#define FH0 4
#define FH1 5
#define FO1 6

static __device__ __forceinline__ f4v mfma16(h8v a, h8v b, f4v c) {
  return __builtin_amdgcn_mfma_f32_16x16x32_f16(a, b, c, 0, 0, 0);
}
static __device__ __forceinline__ f4v fzero() { f4v z; z[0]=0.f; z[1]=0.f; z[2]=0.f; z[3]=0.f; return z; }
// fast-rcp transcendentals (v_rcp_f32 ~1ulp; budget is 2e-3 -> fine)
static __device__ __forceinline__ float rcpf(float x) { return __builtin_amdgcn_rcpf(x); }
static __device__ __forceinline__ float sigm(float x) { return rcpf(1.0f + __expf(-x)); }
static __device__ __forceinline__ float tanh2(float x) { return 1.0f - 2.0f * rcpf(1.0f + __expf(2.0f * x)); }

// Fragment-order convert all 8 weight matrices (layout [tile][kc 32][lr 16] of h8v)
// and zero the group flags.
__global__ void conv_w(const float* __restrict__ whh0, const float* __restrict__ wih1,
                       const float* __restrict__ whh1, const float* __restrict__ ow1,
                       const float* __restrict__ ew2,  const float* __restrict__ ew3,
                       const float* __restrict__ hiw,  const float* __restrict__ ciw,
                       f16* __restrict__ dst, int* __restrict__ flags) {
  int i = blockIdx.x * 256 + threadIdx.x;   // 0 .. FRAG_TOTAL-1
  if (blockIdx.x == 0 && threadIdx.x < 128) flags[threadIdx.x] = 0;
  if (i >= FRAG_TOTAL) return;
  const float* src; int base;
  if      (i < 262144)  { src = whh0; base = 0; }
  else if (i < 524288)  { src = wih1; base = 262144; }
  else if (i < 786432)  { src = whh1; base = 524288; }
  else if (i < 819200)  { src = ow1;  base = 786432; }
  else if (i < 884736)  { src = ew2;  base = 819200; }
  else if (i < 950272)  { src = ew3;  base = 884736; }
  else if (i < 1081344) { src = hiw;  base = 950272; }
  else                  { src = ciw;  base = 1081344; }
  int e = i - base;
  int row = e >> 8, col = e & 255;
  int idx = base + ((((row >> 4) << 5) + (col >> 3)) << 7) + ((row & 15) << 3) + (col & 7);
  dst[idx] = (f16)src[e];
}

// group-flag protocol: cumulative counters, release/acquire at SYSTEM scope (G16).
#define RELF(fi)                                                               \
  do { __syncthreads();                                                        \
       if (tid == 0) __hip_atomic_fetch_add(&flg[fi], 1, __ATOMIC_RELEASE,     \
                                            __HIP_MEMORY_SCOPE_SYSTEM);        \
  } while (0)
#define WAITF(fi, tgt)                                                         \
  do { if (tid == 0) {                                                         \
         while (__hip_atomic_load(&flg[fi], __ATOMIC_RELAXED,                  \
                                  __HIP_MEMORY_SCOPE_SYSTEM) < (tgt))          \
           __builtin_amdgcn_s_sleep(2);                                        \
         (void)__hip_atomic_load(&flg[fi], __ATOMIC_ACQUIRE,                   \
                                 __HIP_MEMORY_SCOPE_SYSTEM);                   \
       }                                                                       \
       __syncthreads();                                                        \
  } while (0)

__global__ __launch_bounds__(NTHR, 1)
void traj_kernel(const float* __restrict__ x,
                 const float* __restrict__ ew1, const float* __restrict__ eb1,
                 const float* __restrict__ eb2, const float* __restrict__ eb3,
                 const float* __restrict__ hib, const float* __restrict__ cib,
                 const float* __restrict__ wih0,
                 const float* __restrict__ bih0, const float* __restrict__ bhh0,
                 const float* __restrict__ bih1, const float* __restrict__ bhh1,
                 const float* __restrict__ ob1, const float* __restrict__ ow2,
                 const float* __restrict__ ob2, const float* __restrict__ stok,
                 f16* __restrict__ ws, int* __restrict__ flags,
                 float* __restrict__ out)
{
  __shared__ __align__(16) f16 WL[13 * 4096];    // 104 KB weight tiles
  __shared__ __align__(16) float decsL[512 * 4]; // 8 KB dec stage (f32)
  __shared__ __align__(16) f16 o1s[32 * 136];    // 8.5 KB o1 gather
  __shared__ float w2s[384];
  __shared__ float ob2s[4];

  const int tid  = threadIdx.x;
  const int bid  = blockIdx.x;
  const int g    = (bid & 7) + ((bid >> 7) << 3);   // 0..15
  const int m    = (bid >> 3) & 15;                 // member 0..15
  const int wv   = tid >> 6;
  const int lane = tid & 63;
  const int lr   = lane & 15;
  const int lg   = lane >> 4;

  int* flg = flags + g * 8;
  const int dcol = 16 * m + lr;

  f16* e1g = ws + H0F + g * 131072;
  f16* e2g = ws + H1F + g * 131072;
  f16* e3g = ws + H0F + (16 + g) * 131072;
  f16* o1g = ws + O1F + g * 65536;
  float* decb = (float*)(ws + DECF) + g * 4096;

  // ---- per-lane constants ----
  float wihr[4][3], b0r[4], b1r[4];
#pragma unroll
  for (int G = 0; G < 4; ++G) {
    const int gc = G * 256 + dcol;
    wihr[G][0] = wih0[gc * 3 + 0];
    wihr[G][1] = wih0[gc * 3 + 1];
    wihr[G][2] = wih0[gc * 3 + 2];
    b0r[G] = bih0[gc] + bhh0[gc];
    b1r[G] = bih1[gc] + bhh1[gc];
  }
  const float ob1r = ob1[((m & 7) << 4) + lr];
  if (tid < 384) w2s[tid] = ow2[tid];
  if (tid < 3)   ob2s[tid] = ob2[tid];

  auto cptile = [&](int slot, int srcF) {
    ((h8v*)(WL + slot * 4096))[tid] = *(const h8v*)(ws + srcF + tid * 8);
  };
  auto BF = [&](int slot, int k) -> h8v {
    return ((const h8v*)WL)[slot * 512 + ((k << 2) + lg) * 16 + lr];
  };
  auto loadA8 = [&](const f16* gb, int R0, h8v* a) {
    const f16* p0 = gb + (lg >> 1) * 8192 + (size_t)(R0 + lr) * 16 + (lg & 1) * 8;
#pragma unroll
    for (int k = 0; k < 8; ++k) a[k] = *(const h8v*)(p0 + k * 16384);
  };

  // ================= setup: encoder + h/c init (exchange-based) =================
  cptile(0, EW2F + m * 4096);
  cptile(1, EW3F + m * 4096);
  cptile(2, HIWF + m * 4096);
  cptile(3, HIWF + (16 + m) * 4096);
  cptile(4, CIWF + m * 4096);
  cptile(5, CIWF + (16 + m) * 4096);
  __syncthreads();

  { // e1 (VALU)
    const int r = tid;
    float xr[7];
#pragma unroll
    for (int k = 0; k < 7; ++k) xr[k] = x[(size_t)(g * 512 + r) * 7 + k];
    f16 ev[16];
#pragma unroll
    for (int i2 = 0; i2 < 16; ++i2) {
      const int c = 16 * m + i2;
      float a = eb1[c];
#pragma unroll
      for (int k = 0; k < 7; ++k) a += xr[k] * ew1[c * 7 + k];
      ev[i2] = (f16)fmaxf(a, 0.0f);
    }
    *(h8v*)(e1g + m * 8192 + r * 16)     = *(h8v*)&ev[0];
    *(h8v*)(e1g + m * 8192 + r * 16 + 8) = *(h8v*)&ev[8];
  }
  RELF(FE1); WAITF(FE1, 16);

  { // e2 = relu(e1 @ ew2^T)
    const float bb = eb2[dcol];
#pragma unroll
    for (int mt = 0; mt < 4; ++mt) {
      const int R0 = wv * 64 + mt * 16;
      h8v a[8]; loadA8(e1g, R0, a);
      f4v acc = fzero();
#pragma unroll
      for (int k = 0; k < 8; ++k) acc = mfma16(a[k], BF(0, k), acc);
#pragma unroll
      for (int j = 0; j < 4; ++j)
        e2g[m * 8192 + (R0 + 4 * lg + j) * 16 + lr] = (f16)fmaxf(acc[j] + bb, 0.0f);
    }
  }
  RELF(FE2); WAITF(FE2, 16);

  { // e3 = relu(e2 @ ew3^T)
    const float bb = eb3[dcol];
#pragma unroll
    for (int mt = 0; mt < 4; ++mt) {
      const int R0 = wv * 64 + mt * 16;
      h8v a[8]; loadA8(e2g, R0, a);
      f4v acc = fzero();
#pragma unroll
      for (int k = 0; k < 8; ++k) acc = mfma16(a[k], BF(1, k), acc);
#pragma unroll
      for (int j = 0; j < 4; ++j)
        e3g[m * 8192 + (R0 + 4 * lg + j) * 16 + lr] = (f16)fmaxf(acc[j] + bb, 0.0f);
    }
  }
  RELF(FE3); WAITF(FE3, 16);

  // h/c init from e3
  float c0v[4][4], c1v[4][4];
  {
    f16* h0g0 = ws + H0F + g * 131072;   // parity-0 h0
    f16* h1g0 = ws + H1F + g * 131072;   // parity-0 h1
    const float bh0 = hib[dcol], bh1 = hib[256 + dcol];
    const float bc0 = cib[dcol], bc1 = cib[256 + dcol];
#pragma unroll
    for (int mt = 0; mt < 4; ++mt) {
      const int R0 = wv * 64 + mt * 16;
      h8v a[8]; loadA8(e3g, R0, a);
      f4v aH = fzero(), aC = fzero();
#pragma unroll
      for (int k = 0; k < 8; ++k) { aH = mfma16(a[k], BF(2, k), aH); aC = mfma16(a[k], BF(4, k), aC); }
#pragma unroll
      for (int j = 0; j < 4; ++j) {
        h0g0[m * 8192 + (R0 + 4 * lg + j) * 16 + lr] = (f16)(aH[j] + bh0);
        c0v[mt][j] = aC[j] + bc0;
      }
      aH = fzero(); aC = fzero();
#pragma unroll
      for (int k = 0; k < 8; ++k) { aH = mfma16(a[k], BF(3, k), aH); aC = mfma16(a[k], BF(5, k), aC); }
#pragma unroll
      for (int j = 0; j < 4; ++j) {
        h1g0[m * 8192 + (R0 + 4 * lg + j) * 16 + lr] = (f16)(aH[j] + bh1);
        c1v[mt][j] = aC[j] + bc1;
      }
    }
    if (tid < 32) { // dec(0) = start_token (parity 0, f32)
      f4v d; d[0] = stok[0]; d[1] = stok[1]; d[2] = stok[2]; d[3] = 0.f;
      *(f4v*)(decb + (m * 32 + tid) * 4) = d;
    }
  }
  RELF(FDEC);

  // permanent weight tiles
#pragma unroll
  for (int G = 0; G < 4; ++G) {
    cptile(G,     W0F  + (G * 16 + m) * 4096);
    cptile(4 + G, W1IF + (G * 16 + m) * 4096);
    cptile(8 + G, W1HF + (G * 16 + m) * 4096);
  }
  cptile(12, OW1F + (m & 7) * 4096);
  __syncthreads();

  // ---- prologue: all init state visible, precompute G0(0) = h0(0) @ W0 ----
  f4v g0a[4][4];   // persistent: gates-from-h0 GEMM for the *current* step
  WAITF(FDEC, 16);
  {
    const f16* h0old0 = ws + H0F + g * 131072;   // parity 0
#pragma unroll
    for (int mt = 0; mt < 4; ++mt) {
      const int R0 = wv * 64 + mt * 16;
      h8v a[8]; loadA8(h0old0, R0, a);
#pragma unroll
      for (int G = 0; G < 4; ++G) g0a[mt][G] = fzero();
#pragma unroll
      for (int k = 0; k < 8; ++k) {
        g0a[mt][0] = mfma16(a[k], BF(0, k), g0a[mt][0]);
        g0a[mt][1] = mfma16(a[k], BF(1, k), g0a[mt][1]);
        g0a[mt][2] = mfma16(a[k], BF(2, k), g0a[mt][2]);
        g0a[mt][3] = mfma16(a[k], BF(3, k), g0a[mt][3]);
      }
    }
  }

  // ================= T = 200 sequential decoder steps =================
#pragma unroll 1
  for (int t = 0; t < TT; ++t) {
    const int p = t & 1;
    f16* h0new = ws + H0F + ((p ^ 1) * 16 + g) * 131072;
    f16* h1old = ws + H1F + (p * 16 + g) * 131072;
    f16* h1new = ws + H1F + ((p ^ 1) * 16 + g) * 131072;
    const float* decp = decb + p * 2048;
    float* decn = decb + (p ^ 1) * 2048;

    f4v ph[4][4];   // layer-1 gates accumulator

    // ---- Phh mt 0,1 (= h1old @ W1h) : hides the FDEC wait ----
#pragma unroll
    for (int mt = 0; mt < 2; ++mt) {
      const int R0 = wv * 64 + mt * 16;
      h8v a[8]; loadA8(h1old, R0, a);
#pragma unroll
      for (int G = 0; G < 4; ++G) ph[mt][G] = fzero();
#pragma unroll
      for (int k = 0; k < 8; ++k) {
        ph[mt][0] = mfma16(a[k], BF(8,  k), ph[mt][0]);
        ph[mt][1] = mfma16(a[k], BF(9,  k), ph[mt][1]);
        ph[mt][2] = mfma16(a[k], BF(10, k), ph[mt][2]);
        ph[mt][3] = mfma16(a[k], BF(11, k), ph[mt][3]);
      }
    }
    WAITF(FDEC, 16 * (t + 1));
    *(f4v*)(decsL + tid * 4) = *(const f4v*)(decp + tid * 4);
    __syncthreads();

    // ---- E0: consume precomputed g0a + dec -> h0new ----
#pragma unroll
    for (int mt = 0; mt < 4; ++mt) {
      const int R0 = wv * 64 + mt * 16;
#pragma unroll
      for (int j = 0; j < 4; ++j) {
        const int row = R0 + 4 * lg + j;
        f4v d4 = *(const f4v*)(decsL + row * 4);
        const float d0 = d4[0], d1 = d4[1], d2 = d4[2];
        float gi = g0a[mt][0][j] + b0r[0] + d0 * wihr[0][0] + d1 * wihr[0][1] + d2 * wihr[0][2];
        float gf = g0a[mt][1][j] + b0r[1] + d0 * wihr[1][0] + d1 * wihr[1][1] + d2 * wihr[1][2];
        float gg = g0a[mt][2][j] + b0r[2] + d0 * wihr[2][0] + d1 * wihr[2][1] + d2 * wihr[2][2];
        float go = g0a[mt][3][j] + b0r[3] + d0 * wihr[3][0] + d1 * wihr[3][1] + d2 * wihr[3][2];
        float cn = sigm(gf) * c0v[mt][j] + sigm(gi) * tanh2(gg);
        c0v[mt][j] = cn;
        __builtin_nontemporal_store((f16)(sigm(go) * tanh2(cn)),
                                    h0new + m * 8192 + row * 16 + lr);
      }
    }
    RELF(FH0);

    // ---- Phh mt 2,3 : hides the FH0 wait ----
#pragma unroll
    for (int mt = 2; mt < 4; ++mt) {
      const int R0 = wv * 64 + mt * 16;
      h8v a[8]; loadA8(h1old, R0, a);
#pragma unroll
      for (int G = 0; G < 4; ++G) ph[mt][G] = fzero();
#pragma unroll
      for (int k = 0; k < 8; ++k) {
        ph[mt][0] = mfma16(a[k], BF(8,  k), ph[mt][0]);
        ph[mt][1] = mfma16(a[k], BF(9,  k), ph[mt][1]);
        ph[mt][2] = mfma16(a[k], BF(10, k), ph[mt][2]);
        ph[mt][3] = mfma16(a[k], BF(11, k), ph[mt][3]);
      }
    }
    WAITF(FH0, 16 * (t + 1));

    // ---- L1: ph += h0new @ W1i ; elementwise -> h1new ----
#pragma unroll
    for (int mt = 0; mt < 4; ++mt) {
      const int R0 = wv * 64 + mt * 16;
      h8v a[8]; loadA8(h0new, R0, a);
#pragma unroll
      for (int k = 0; k < 8; ++k) {
        ph[mt][0] = mfma16(a[k], BF(4, k), ph[mt][0]);
        ph[mt][1] = mfma16(a[k], BF(5, k), ph[mt][1]);
        ph[mt][2] = mfma16(a[k], BF(6, k), ph[mt][2]);
        ph[mt][3] = mfma16(a[k], BF(7, k), ph[mt][3]);
      }
#pragma unroll
      for (int j = 0; j < 4; ++j) {
        const int row = R0 + 4 * lg + j;
        float gi = ph[mt][0][j] + b1r[0];
        float gf = ph[mt][1][j] + b1r[1];
        float gg = ph[mt][2][j] + b1r[2];
        float go = ph[mt][3][j] + b1r[3];
        float cn = sigm(gf) * c1v[mt][j] + sigm(gi) * tanh2(gg);
        c1v[mt][j] = cn;
        __builtin_nontemporal_store((f16)(sigm(go) * tanh2(cn)),
                                    h1new + m * 8192 + row * 16 + lr);
      }
    }
    RELF(FH1);

    // ---- G0(t+1) = h0new @ W0 : hides the FH1 wait ----
#pragma unroll
    for (int mt = 0; mt < 4; ++mt) {
      const int R0 = wv * 64 + mt * 16;
      h8v a[8]; loadA8(h0new, R0, a);
#pragma unroll
      for (int G = 0; G < 4; ++G) g0a[mt][G] = fzero();
#pragma unroll
      for (int k = 0; k < 8; ++k) {
        g0a[mt][0] = mfma16(a[k], BF(0, k), g0a[mt][0]);
        g0a[mt][1] = mfma16(a[k], BF(1, k), g0a[mt][1]);
        g0a[mt][2] = mfma16(a[k], BF(2, k), g0a[mt][2]);
        g0a[mt][3] = mfma16(a[k], BF(3, k), g0a[mt][3]);
      }
    }
    WAITF(FH1, 16 * (t + 1));

    // ---- head: o1 = relu(h1new @ ow1^T); pair (m, m+8) splits rows ----
    {
      const int Rh = ((m >> 3) << 8) + wv * 32;
#pragma unroll
      for (int mt2 = 0; mt2 < 2; ++mt2) {
        const int R0 = Rh + mt2 * 16;
        h8v a[8]; loadA8(h1new, R0, a);
        f4v acc = fzero();
#pragma unroll
        for (int k = 0; k < 8; ++k) acc = mfma16(a[k], BF(12, k), acc);
#pragma unroll
        for (int j = 0; j < 4; ++j)
          __builtin_nontemporal_store((f16)fmaxf(acc[j] + ob1r, 0.0f),
                                      o1g + (m & 7) * 8192 + (R0 + 4 * lg + j) * 16 + lr);
      }
    }
    RELF(FO1);
    WAITF(FO1, 16 * (t + 1));

    // ---- final: out = relu-o1 @ out_w2^T + b2 for member's 32 rows; feed dec ----
    {
      const int r32 = tid >> 4, t8 = (tid & 15) >> 1, hf = tid & 1;
      *(h8v*)(o1s + r32 * 136 + t8 * 16 + hf * 8) =
          *(const h8v*)(o1g + t8 * 8192 + (m * 32 + r32) * 16 + hf * 8);
    }
    __syncthreads();
    {
      const int r = tid >> 4, jj = tid & 15;
      float a0 = 0.f, a1 = 0.f, a2 = 0.f;
#pragma unroll
      for (int kk = 0; kk < 8; ++kk) {
        const int k = jj * 8 + kk;
        const float ov = (float)o1s[r * 136 + k];
        a0 += ov * w2s[k];
        a1 += ov * w2s[128 + k];
        a2 += ov * w2s[256 + k];
      }
#pragma unroll
      for (int s = 8; s >= 1; s >>= 1) {
        a0 += __shfl_xor(a0, s);
        a1 += __shfl_xor(a1, s);
        a2 += __shfl_xor(a2, s);
      }
      if (jj == 0) {
        a0 += ob2s[0]; a1 += ob2s[1]; a2 += ob2s[2];
        float* op = out + ((size_t)(g * 512 + m * 32 + r) * TT + t) * 3;
        op[0] = a0; op[1] = a1; op[2] = a2;
        f4v d; d[0] = a0; d[1] = a1; d[2] = a2; d[3] = 0.f;
        __builtin_nontemporal_store(d, (f4v*)(decn + (m * 32 + r) * 4));
      }
    }
    RELF(FDEC);
  }
}

extern "C" void kernel_launch(void* const* d_in, const int* in_sizes, int n_in,
                              void* d_out, int out_size, void* d_ws, size_t ws_size,
                              hipStream_t stream) {
  (void)in_sizes; (void)n_in; (void)out_size; (void)ws_size;
  f16* wk = (f16*)d_ws;
  int* flags = (int*)((char*)d_ws + (size_t)FLGF * 2);
  conv_w<<<(FRAG_TOTAL + 255) / 256, 256, 0, stream>>>(
      (const float*)d_in[12], (const float*)d_in[15],
      (const float*)d_in[16], (const float*)d_in[19],
      (const float*)d_in[3],  (const float*)d_in[5],
      (const float*)d_in[7],  (const float*)d_in[9],
      wk, flags);
  traj_kernel<<<NWG, NTHR, 0, stream>>>(
      (const float*)d_in[0],
      (const float*)d_in[1],  (const float*)d_in[2],
      (const float*)d_in[4],  (const float*)d_in[6],
      (const float*)d_in[8],  (const float*)d_in[10],
      (const float*)d_in[11],
      (const float*)d_in[13], (const float*)d_in[14],
      (const float*)d_in[17], (const float*)d_in[18],
      (const float*)d_in[20], (const float*)d_in[21],
      (const float*)d_in[22], (const float*)d_in[23],
      wk, flags, (float*)d_out);
}

// Round 10
// 9248.061 us; speedup vs baseline: 1.5286x; 1.5286x over previous
//
#include <hip/hip_runtime.h>

typedef _Float16 f16;
typedef f16 h8v __attribute__((ext_vector_type(8)));
typedef f16 h4v __attribute__((ext_vector_type(4)));
typedef float f4v __attribute__((ext_vector_type(4)));

#define TT 200
#define NTHR 512
#define NWG 256

// ---- d_ws layout (f16-element offsets) ----
#define W0F   0          // w_hh0  frag [64 tiles][512 h8v]
#define W1IF  262144     // w_ih1
#define W1HF  524288     // w_hh1
#define OW1F  786432     // out_w1 frag [8 tiles]
#define EW2F  819200     // enc_w2 frag [16 tiles]
#define EW3F  884736     // enc_w3 frag [16 tiles]
#define HIWF  950272     // hinit_w frag [32 tiles]
#define CIWF  1081344    // cinit_w frag [32 tiles]
#define FRAG_TOTAL 1212416  // == CIWF + 131072; conv_w must cover ALL of it
#define H0F   1212416    // h0 state [2 parity][16 g][16 m][512][16] f16
#define H1F   5406720    // h1 state (same shape)
#define O1F   9601024    // o1 [16 g][8 tile][512][16] f16
#define DECF  10649600   // dec [16 g][2 parity][512][4] FLOAT (occupies 131072 f16 units)
#define FLGF  10780672   // int32 flags [16 g][8] at byte offset FLGF*2

// flag indices
#define FE1 0
#define FE2 1
#define FE3 2
#define FDEC 3
#define FH0 4
#define FH1 5
#define FO1 6

static __device__ __forceinline__ f4v mfma16(h8v a, h8v b, f4v c) {
  return __builtin_amdgcn_mfma_f32_16x16x32_f16(a, b, c, 0, 0, 0);
}
static __device__ __forceinline__ f4v fzero() { f4v z; z[0]=0.f; z[1]=0.f; z[2]=0.f; z[3]=0.f; return z; }
// fast-rcp transcendentals (v_rcp_f32 ~1ulp; budget is 2e-3 -> fine)
static __device__ __forceinline__ float rcpf(float x) { return __builtin_amdgcn_rcpf(x); }
static __device__ __forceinline__ float sigm(float x) { return rcpf(1.0f + __expf(-x)); }
static __device__ __forceinline__ float tanh2(float x) { return 1.0f - 2.0f * rcpf(1.0f + __expf(2.0f * x)); }

// Fragment-order convert all 8 weight matrices (layout [tile][kc 32][lr 16] of h8v)
// and zero the group flags.
__global__ void conv_w(const float* __restrict__ whh0, const float* __restrict__ wih1,
                       const float* __restrict__ whh1, const float* __restrict__ ow1,
                       const float* __restrict__ ew2,  const float* __restrict__ ew3,
                       const float* __restrict__ hiw,  const float* __restrict__ ciw,
                       f16* __restrict__ dst, int* __restrict__ flags) {
  int i = blockIdx.x * 256 + threadIdx.x;   // 0 .. FRAG_TOTAL-1
  if (blockIdx.x == 0 && threadIdx.x < 128) flags[threadIdx.x] = 0;
  if (i >= FRAG_TOTAL) return;
  const float* src; int base;
  if      (i < 262144)  { src = whh0; base = 0; }
  else if (i < 524288)  { src = wih1; base = 262144; }
  else if (i < 786432)  { src = whh1; base = 524288; }
  else if (i < 819200)  { src = ow1;  base = 786432; }
  else if (i < 884736)  { src = ew2;  base = 819200; }
  else if (i < 950272)  { src = ew3;  base = 884736; }
  else if (i < 1081344) { src = hiw;  base = 950272; }
  else                  { src = ciw;  base = 1081344; }
  int e = i - base;
  int row = e >> 8, col = e & 255;
  int idx = base + ((((row >> 4) << 5) + (col >> 3)) << 7) + ((row & 15) << 3) + (col & 7);
  dst[idx] = (f16)src[e];
}

// group-flag protocol: cumulative counters, release/acquire at SYSTEM scope (G16).
#define RELF(fi)                                                               \
  do { __syncthreads();                                                        \
       if (tid == 0) __hip_atomic_fetch_add(&flg[fi], 1, __ATOMIC_RELEASE,     \
                                            __HIP_MEMORY_SCOPE_SYSTEM);        \
  } while (0)
#define WAITF(fi, tgt)                                                         \
  do { if (tid == 0) {                                                         \
         while (__hip_atomic_load(&flg[fi], __ATOMIC_RELAXED,                  \
                                  __HIP_MEMORY_SCOPE_SYSTEM) < (tgt))          \
           __builtin_amdgcn_s_sleep(2);                                        \
         (void)__hip_atomic_load(&flg[fi], __ATOMIC_ACQUIRE,                   \
                                 __HIP_MEMORY_SCOPE_SYSTEM);                   \
       }                                                                       \
       __syncthreads();                                                        \
  } while (0)

__global__ __launch_bounds__(NTHR, 1)
void traj_kernel(const float* __restrict__ x,
                 const float* __restrict__ ew1, const float* __restrict__ eb1,
                 const float* __restrict__ eb2, const float* __restrict__ eb3,
                 const float* __restrict__ hib, const float* __restrict__ cib,
                 const float* __restrict__ wih0,
                 const float* __restrict__ bih0, const float* __restrict__ bhh0,
                 const float* __restrict__ bih1, const float* __restrict__ bhh1,
                 const float* __restrict__ ob1, const float* __restrict__ ow2,
                 const float* __restrict__ ob2, const float* __restrict__ stok,
                 f16* __restrict__ ws, int* __restrict__ flags,
                 float* __restrict__ out)
{
  __shared__ __align__(16) f16 WL[13 * 4096];    // 104 KB weight tiles
  __shared__ __align__(16) float decsL[512 * 4]; // 8 KB dec stage (f32)
  __shared__ __align__(16) f16 o1s[32 * 136];    // 8.5 KB o1 gather
  __shared__ float w2s[384];
  __shared__ float b0L[64];                      // member-slice L0 biases [G][lr]
  __shared__ float b1L[64];                      // member-slice L1 biases
  __shared__ float wiL[192];                     // member-slice w_ih0 [G][lr][3]
  __shared__ float ob2s[4];

  const int tid  = threadIdx.x;
  const int bid  = blockIdx.x;
  const int g    = (bid & 7) + ((bid >> 7) << 3);   // 0..15
  const int m    = (bid >> 3) & 15;                 // member 0..15
  const int wv   = tid >> 6;
  const int lane = tid & 63;
  const int lr   = lane & 15;
  const int lg   = lane >> 4;

  int* flg = flags + g * 8;
  const int dcol = 16 * m + lr;

  f16* e1g = ws + H0F + g * 131072;
  f16* e2g = ws + H1F + g * 131072;
  f16* e3g = ws + H0F + (16 + g) * 131072;
  f16* o1g = ws + O1F + g * 65536;
  float* decb = (float*)(ws + DECF) + g * 4096;

  // ---- per-lane constants -> LDS (keeps VGPR pressure under the 128 wall) ----
  if (tid < 64) {
    const int G = tid >> 4, l = tid & 15;
    const int gc = G * 256 + 16 * m + l;
    b0L[tid] = bih0[gc] + bhh0[gc];
    b1L[tid] = bih1[gc] + bhh1[gc];
    wiL[tid * 3 + 0] = wih0[gc * 3 + 0];
    wiL[tid * 3 + 1] = wih0[gc * 3 + 1];
    wiL[tid * 3 + 2] = wih0[gc * 3 + 2];
  }
  const float ob1r = ob1[((m & 7) << 4) + lr];
  if (tid < 384) w2s[tid] = ow2[tid];
  if (tid < 3)   ob2s[tid] = ob2[tid];

  auto cptile = [&](int slot, int srcF) {
    ((h8v*)(WL + slot * 4096))[tid] = *(const h8v*)(ws + srcF + tid * 8);
  };
  auto BF = [&](int slot, int k) -> h8v {
    return ((const h8v*)WL)[slot * 512 + ((k << 2) + lg) * 16 + lr];
  };
  auto loadA8 = [&](const f16* gb, int R0, h8v* a) {
    const f16* p0 = gb + (lg >> 1) * 8192 + (size_t)(R0 + lr) * 16 + (lg & 1) * 8;
#pragma unroll
    for (int k = 0; k < 8; ++k) a[k] = *(const h8v*)(p0 + k * 16384);
  };

  // ================= setup: encoder + h/c init (exchange-based) =================
  cptile(0, EW2F + m * 4096);
  cptile(1, EW3F + m * 4096);
  cptile(2, HIWF + m * 4096);
  cptile(3, HIWF + (16 + m) * 4096);
  cptile(4, CIWF + m * 4096);
  cptile(5, CIWF + (16 + m) * 4096);
  __syncthreads();

  { // e1 (VALU)
    const int r = tid;
    float xr[7];
#pragma unroll
    for (int k = 0; k < 7; ++k) xr[k] = x[(size_t)(g * 512 + r) * 7 + k];
    f16 ev[16];
#pragma unroll
    for (int i2 = 0; i2 < 16; ++i2) {
      const int c = 16 * m + i2;
      float a = eb1[c];
#pragma unroll
      for (int k = 0; k < 7; ++k) a += xr[k] * ew1[c * 7 + k];
      ev[i2] = (f16)fmaxf(a, 0.0f);
    }
    *(h8v*)(e1g + m * 8192 + r * 16)     = *(h8v*)&ev[0];
    *(h8v*)(e1g + m * 8192 + r * 16 + 8) = *(h8v*)&ev[8];
  }
  RELF(FE1); WAITF(FE1, 16);

  { // e2 = relu(e1 @ ew2^T)
    const float bb = eb2[dcol];
#pragma unroll
    for (int mt = 0; mt < 4; ++mt) {
      const int R0 = wv * 64 + mt * 16;
      h8v a[8]; loadA8(e1g, R0, a);
      f4v acc = fzero();
#pragma unroll
      for (int k = 0; k < 8; ++k) acc = mfma16(a[k], BF(0, k), acc);
#pragma unroll
      for (int j = 0; j < 4; ++j)
        e2g[m * 8192 + (R0 + 4 * lg + j) * 16 + lr] = (f16)fmaxf(acc[j] + bb, 0.0f);
    }
  }
  RELF(FE2); WAITF(FE2, 16);

  { // e3 = relu(e2 @ ew3^T)
    const float bb = eb3[dcol];
#pragma unroll
    for (int mt = 0; mt < 4; ++mt) {
      const int R0 = wv * 64 + mt * 16;
      h8v a[8]; loadA8(e2g, R0, a);
      f4v acc = fzero();
#pragma unroll
      for (int k = 0; k < 8; ++k) acc = mfma16(a[k], BF(1, k), acc);
#pragma unroll
      for (int j = 0; j < 4; ++j)
        e3g[m * 8192 + (R0 + 4 * lg + j) * 16 + lr] = (f16)fmaxf(acc[j] + bb, 0.0f);
    }
  }
  RELF(FE3); WAITF(FE3, 16);

  // h/c init from e3
  float c0v[4][4], c1v[4][4];
  {
    f16* h0g0 = ws + H0F + g * 131072;   // parity-0 h0
    f16* h1g0 = ws + H1F + g * 131072;   // parity-0 h1
    const float bh0 = hib[dcol], bh1 = hib[256 + dcol];
    const float bc0 = cib[dcol], bc1 = cib[256 + dcol];
#pragma unroll
    for (int mt = 0; mt < 4; ++mt) {
      const int R0 = wv * 64 + mt * 16;
      h8v a[8]; loadA8(e3g, R0, a);
      f4v aH = fzero(), aC = fzero();
#pragma unroll
      for (int k = 0; k < 8; ++k) { aH = mfma16(a[k], BF(2, k), aH); aC = mfma16(a[k], BF(4, k), aC); }
#pragma unroll
      for (int j = 0; j < 4; ++j) {
        h0g0[m * 8192 + (R0 + 4 * lg + j) * 16 + lr] = (f16)(aH[j] + bh0);
        c0v[mt][j] = aC[j] + bc0;
      }
      aH = fzero(); aC = fzero();
#pragma unroll
      for (int k = 0; k < 8; ++k) { aH = mfma16(a[k], BF(3, k), aH); aC = mfma16(a[k], BF(5, k), aC); }
#pragma unroll
      for (int j = 0; j < 4; ++j) {
        h1g0[m * 8192 + (R0 + 4 * lg + j) * 16 + lr] = (f16)(aH[j] + bh1);
        c1v[mt][j] = aC[j] + bc1;
      }
    }
    if (tid < 32) { // dec(0) = start_token (parity 0, f32)
      f4v d; d[0] = stok[0]; d[1] = stok[1]; d[2] = stok[2]; d[3] = 0.f;
      *(f4v*)(decb + (m * 32 + tid) * 4) = d;
    }
  }
  RELF(FDEC);

  // permanent weight tiles
#pragma unroll
  for (int G = 0; G < 4; ++G) {
    cptile(G,     W0F  + (G * 16 + m) * 4096);
    cptile(4 + G, W1IF + (G * 16 + m) * 4096);
    cptile(8 + G, W1HF + (G * 16 + m) * 4096);
  }
  cptile(12, OW1F + (m & 7) * 4096);
  __syncthreads();

  // ---- prologue: all init state visible; precompute g0(0) = h0(0) @ W0 ----
  f4v g0a[4][4];
  WAITF(FDEC, 16);
  {
    const f16* h0old0 = ws + H0F + g * 131072;   // parity 0
#pragma unroll
    for (int mt = 0; mt < 4; ++mt) {
      const int R0 = wv * 64 + mt * 16;
      h8v a[8]; loadA8(h0old0, R0, a);
#pragma unroll
      for (int G = 0; G < 4; ++G) g0a[mt][G] = fzero();
#pragma unroll
      for (int k = 0; k < 8; ++k) {
        g0a[mt][0] = mfma16(a[k], BF(0, k), g0a[mt][0]);
        g0a[mt][1] = mfma16(a[k], BF(1, k), g0a[mt][1]);
        g0a[mt][2] = mfma16(a[k], BF(2, k), g0a[mt][2]);
        g0a[mt][3] = mfma16(a[k], BF(3, k), g0a[mt][3]);
      }
    }
  }

  // ================= T = 200 sequential decoder steps =================
  // Sync-cover schedule (all GEMM slices legal at their position):
  //   FDEC <- g0 mt3 (tail) ; FH0 <- Phh mt0,1 ; FH1 <- g0 mt0,1 ; FO1 <- g0 mt2.
  // g0a (64 reg) is consumed at E0 before ph (32 reg) is born -> peak fits 128 VGPR.
#pragma unroll 1
  for (int t = 0; t < TT; ++t) {
    const int p = t & 1;
    f16* h0new = ws + H0F + ((p ^ 1) * 16 + g) * 131072;
    f16* h1old = ws + H1F + (p * 16 + g) * 131072;
    f16* h1new = ws + H1F + ((p ^ 1) * 16 + g) * 131072;
    const float* decp = decb + p * 2048;
    float* decn = decb + (p ^ 1) * 2048;

    // (A) dec ready (covered by g0 mt3 of previous iteration)
    WAITF(FDEC, 16 * (t + 1));
    *(f4v*)(decsL + tid * 4) = *(const f4v*)(decp + tid * 4);
    __syncthreads();

    // (B) E0: consume g0a + dec -> h0new
    {
      float cb0[4], cw[4][3];
#pragma unroll
      for (int G = 0; G < 4; ++G) {
        cb0[G]   = b0L[G * 16 + lr];
        cw[G][0] = wiL[(G * 16 + lr) * 3 + 0];
        cw[G][1] = wiL[(G * 16 + lr) * 3 + 1];
        cw[G][2] = wiL[(G * 16 + lr) * 3 + 2];
      }
#pragma unroll
      for (int mt = 0; mt < 4; ++mt) {
        const int R0 = wv * 64 + mt * 16;
#pragma unroll
        for (int j = 0; j < 4; ++j) {
          const int row = R0 + 4 * lg + j;
          f4v d4 = *(const f4v*)(decsL + row * 4);
          float gi = g0a[mt][0][j] + cb0[0] + d4[0]*cw[0][0] + d4[1]*cw[0][1] + d4[2]*cw[0][2];
          float gf = g0a[mt][1][j] + cb0[1] + d4[0]*cw[1][0] + d4[1]*cw[1][1] + d4[2]*cw[1][2];
          float gg = g0a[mt][2][j] + cb0[2] + d4[0]*cw[2][0] + d4[1]*cw[2][1] + d4[2]*cw[2][2];
          float go = g0a[mt][3][j] + cb0[3] + d4[0]*cw[3][0] + d4[1]*cw[3][1] + d4[2]*cw[3][2];
          float cn = sigm(gf) * c0v[mt][j] + sigm(gi) * tanh2(gg);
          c0v[mt][j] = cn;
          __builtin_nontemporal_store((f16)(sigm(go) * tanh2(cn)),
                                      h0new + m * 8192 + row * 16 + lr);
        }
      }
    }
    RELF(FH0);

    // (C) Phh mt0,1 = h1old @ W1h : covers the FH0 wait
    f4v ph[2][4];
#pragma unroll
    for (int mt = 0; mt < 2; ++mt) {
      const int R0 = wv * 64 + mt * 16;
      h8v a[8]; loadA8(h1old, R0, a);
#pragma unroll
      for (int G = 0; G < 4; ++G) ph[mt][G] = fzero();
#pragma unroll
      for (int k = 0; k < 8; ++k) {
        ph[mt][0] = mfma16(a[k], BF(8,  k), ph[mt][0]);
        ph[mt][1] = mfma16(a[k], BF(9,  k), ph[mt][1]);
        ph[mt][2] = mfma16(a[k], BF(10, k), ph[mt][2]);
        ph[mt][3] = mfma16(a[k], BF(11, k), ph[mt][3]);
      }
    }
    WAITF(FH0, 16 * (t + 1));

    // (D) L1
    {
      float cb1[4];
#pragma unroll
      for (int G = 0; G < 4; ++G) cb1[G] = b1L[G * 16 + lr];
      // mt 0,1: += W1i, then elementwise
#pragma unroll
      for (int mt = 0; mt < 2; ++mt) {
        const int R0 = wv * 64 + mt * 16;
        h8v a[8]; loadA8(h0new, R0, a);
#pragma unroll
        for (int k = 0; k < 8; ++k) {
          ph[mt][0] = mfma16(a[k], BF(4, k), ph[mt][0]);
          ph[mt][1] = mfma16(a[k], BF(5, k), ph[mt][1]);
          ph[mt][2] = mfma16(a[k], BF(6, k), ph[mt][2]);
          ph[mt][3] = mfma16(a[k], BF(7, k), ph[mt][3]);
        }
#pragma unroll
        for (int j = 0; j < 4; ++j) {
          const int row = R0 + 4 * lg + j;
          float cn = sigm(ph[mt][1][j] + cb1[1]) * c1v[mt][j]
                   + sigm(ph[mt][0][j] + cb1[0]) * tanh2(ph[mt][2][j] + cb1[2]);
          c1v[mt][j] = cn;
          __builtin_nontemporal_store((f16)(sigm(ph[mt][3][j] + cb1[3]) * tanh2(cn)),
                                      h1new + m * 8192 + row * 16 + lr);
        }
      }
      // mt 2,3: fresh accumulators, W1h + W1i
#pragma unroll
      for (int mt = 2; mt < 4; ++mt) {
        const int R0 = wv * 64 + mt * 16;
        f4v ai = fzero(), af = fzero(), ag = fzero(), ao = fzero();
        {
          h8v a[8]; loadA8(h1old, R0, a);
#pragma unroll
          for (int k = 0; k < 8; ++k) {
            ai = mfma16(a[k], BF(8,  k), ai);
            af = mfma16(a[k], BF(9,  k), af);
            ag = mfma16(a[k], BF(10, k), ag);
            ao = mfma16(a[k], BF(11, k), ao);
          }
        }
        {
          h8v a[8]; loadA8(h0new, R0, a);
#pragma unroll
          for (int k = 0; k < 8; ++k) {
            ai = mfma16(a[k], BF(4, k), ai);
            af = mfma16(a[k], BF(5, k), af);
            ag = mfma16(a[k], BF(6, k), ag);
            ao = mfma16(a[k], BF(7, k), ao);
          }
        }
#pragma unroll
        for (int j = 0; j < 4; ++j) {
          const int row = R0 + 4 * lg + j;
          float cn = sigm(af[j] + cb1[1]) * c1v[mt][j]
                   + sigm(ai[j] + cb1[0]) * tanh2(ag[j] + cb1[2]);
          c1v[mt][j] = cn;
          __builtin_nontemporal_store((f16)(sigm(ao[j] + cb1[3]) * tanh2(cn)),
                                      h1new + m * 8192 + row * 16 + lr);
        }
      }
    }
    RELF(FH1);

    // (E) g0(t+1) mt0,1 = h0new @ W0 : covers the FH1 wait
#pragma unroll
    for (int mt = 0; mt < 2; ++mt) {
      const int R0 = wv * 64 + mt * 16;
      h8v a[8]; loadA8(h0new, R0, a);
#pragma unroll
      for (int G = 0; G < 4; ++G) g0a[mt][G] = fzero();
#pragma unroll
      for (int k = 0; k < 8; ++k) {
        g0a[mt][0] = mfma16(a[k], BF(0, k), g0a[mt][0]);
        g0a[mt][1] = mfma16(a[k], BF(1, k), g0a[mt][1]);
        g0a[mt][2] = mfma16(a[k], BF(2, k), g0a[mt][2]);
        g0a[mt][3] = mfma16(a[k], BF(3, k), g0a[mt][3]);
      }
    }
    WAITF(FH1, 16 * (t + 1));

    // (F) head: o1 = relu(h1new @ ow1^T); pair (m, m+8) splits rows
    {
      const int Rh = ((m >> 3) << 8) + wv * 32;
#pragma unroll
      for (int mt2 = 0; mt2 < 2; ++mt2) {
        const int R0 = Rh + mt2 * 16;
        h8v a[8]; loadA8(h1new, R0, a);
        f4v acc = fzero();
#pragma unroll
        for (int k = 0; k < 8; ++k) acc = mfma16(a[k], BF(12, k), acc);
#pragma unroll
        for (int j = 0; j < 4; ++j)
          __builtin_nontemporal_store((f16)fmaxf(acc[j] + ob1r, 0.0f),
                                      o1g + (m & 7) * 8192 + (R0 + 4 * lg + j) * 16 + lr);
      }
    }
    RELF(FO1);

    // (G) g0(t+1) mt2 : covers the FO1 wait
    {
      const int R0 = wv * 64 + 2 * 16;
      h8v a[8]; loadA8(h0new, R0, a);
#pragma unroll
      for (int G = 0; G < 4; ++G) g0a[2][G] = fzero();
#pragma unroll
      for (int k = 0; k < 8; ++k) {
        g0a[2][0] = mfma16(a[k], BF(0, k), g0a[2][0]);
        g0a[2][1] = mfma16(a[k], BF(1, k), g0a[2][1]);
        g0a[2][2] = mfma16(a[k], BF(2, k), g0a[2][2]);
        g0a[2][3] = mfma16(a[k], BF(3, k), g0a[2][3]);
      }
    }
    WAITF(FO1, 16 * (t + 1));

    // (H) final: out = relu-o1 @ out_w2^T + b2 for member's 32 rows; feed dec
    {
      const int r32 = tid >> 4, t8 = (tid & 15) >> 1, hf = tid & 1;
      *(h8v*)(o1s + r32 * 136 + t8 * 16 + hf * 8) =
          *(const h8v*)(o1g + t8 * 8192 + (m * 32 + r32) * 16 + hf * 8);
    }
    __syncthreads();
    {
      const int r = tid >> 4, jj = tid & 15;
      float a0 = 0.f, a1 = 0.f, a2 = 0.f;
#pragma unroll
      for (int kk = 0; kk < 8; ++kk) {
        const int k = jj * 8 + kk;
        const float ov = (float)o1s[r * 136 + k];
        a0 += ov * w2s[k];
        a1 += ov * w2s[128 + k];
        a2 += ov * w2s[256 + k];
      }
#pragma unroll
      for (int s = 8; s >= 1; s >>= 1) {
        a0 += __shfl_xor(a0, s);
        a1 += __shfl_xor(a1, s);
        a2 += __shfl_xor(a2, s);
      }
      if (jj == 0) {
        a0 += ob2s[0]; a1 += ob2s[1]; a2 += ob2s[2];
        float* op = out + ((size_t)(g * 512 + m * 32 + r) * TT + t) * 3;
        op[0] = a0; op[1] = a1; op[2] = a2;
        f4v d; d[0] = a0; d[1] = a1; d[2] = a2; d[3] = 0.f;
        __builtin_nontemporal_store(d, (f4v*)(decn + (m * 32 + r) * 4));
      }
    }
    RELF(FDEC);

    // (I) g0(t+1) mt3 : covers the next iteration's FDEC wait
    {
      const int R0 = wv * 64 + 3 * 16;
      h8v a[8]; loadA8(h0new, R0, a);
#pragma unroll
      for (int G = 0; G < 4; ++G) g0a[3][G] = fzero();
#pragma unroll
      for (int k = 0; k < 8; ++k) {
        g0a[3][0] = mfma16(a[k], BF(0, k), g0a[3][0]);
        g0a[3][1] = mfma16(a[k], BF(1, k), g0a[3][1]);
        g0a[3][2] = mfma16(a[k], BF(2, k), g0a[3][2]);
        g0a[3][3] = mfma16(a[k], BF(3, k), g0a[3][3]);
      }
    }
  }
}

extern "C" void kernel_launch(void* const* d_in, const int* in_sizes, int n_in,
                              void* d_out, int out_size, void* d_ws, size_t ws_size,
                              hipStream_t stream) {
  (void)in_sizes; (void)n_in; (void)out_size; (void)ws_size;
  f16* wk = (f16*)d_ws;
  int* flags = (int*)((char*)d_ws + (size_t)FLGF * 2);
  conv_w<<<(FRAG_TOTAL + 255) / 256, 256, 0, stream>>>(
      (const float*)d_in[12], (const float*)d_in[15],
      (const float*)d_in[16], (const float*)d_in[19],
      (const float*)d_in[3],  (const float*)d_in[5],
      (const float*)d_in[7],  (const float*)d_in[9],
      wk, flags);
  traj_kernel<<<NWG, NTHR, 0, stream>>>(
      (const float*)d_in[0],
      (const float*)d_in[1],  (const float*)d_in[2],
      (const float*)d_in[4],  (const float*)d_in[6],
      (const float*)d_in[8],  (const float*)d_in[10],
      (const float*)d_in[11],
      (const float*)d_in[13], (const float*)d_in[14],
      (const float*)d_in[17], (const float*)d_in[18],
      (const float*)d_in[20], (const float*)d_in[21],
      (const float*)d_in[22], (const float*)d_in[23],
      wk, flags, (float*)d_out);
}

// Round 11
// 5213.793 us; speedup vs baseline: 2.7114x; 1.7738x over previous
//
#include <hip/hip_runtime.h>

typedef _Float16 f16;
typedef f16 h8v __attribute__((ext_vector_type(8)));
typedef f16 h4v __attribute__((ext_vector_type(4)));
typedef float f4v __attribute__((ext_vector_type(4)));

#define TT 200
#define NTHR 512
#define NWG 256

// ---- d_ws layout (f16-element offsets) ----
#define W0F   0          // w_hh0  frag [64 tiles][512 h8v]
#define W1IF  262144     // w_ih1
#define W1HF  524288     // w_hh1
#define OW1F  786432     // out_w1 frag [8 tiles]
#define EW2F  819200     // enc_w2 frag [16 tiles]
#define EW3F  884736     // enc_w3 frag [16 tiles]
#define HIWF  950272     // hinit_w frag [32 tiles]
#define CIWF  1081344    // cinit_w frag [32 tiles]
#define FRAG_TOTAL 1212416  // == CIWF + 131072; conv_w must cover ALL of it
#define H0F   1212416    // h0 state [2 parity][16 g][16 m][512][16] f16
#define H1F   5406720    // h1 state (same shape)
#define O1F   9601024    // o1 [16 g][8 tile][512][16] f16
#define DECF  10649600   // dec [16 g][2 parity][512][4] FLOAT (occupies 131072 f16 units)
#define FLGF  10780672   // int32 flags [16 g][8] at byte offset FLGF*2

// flag indices
#define FE1 0
#define FE2 1
#define FE3 2
#define FDEC 3
#define FH0 4
#define FH1 5
#define FO1 6

static __device__ __forceinline__ f4v mfma16(h8v a, h8v b, f4v c) {
  return __builtin_amdgcn_mfma_f32_16x16x32_f16(a, b, c, 0, 0, 0);
}
static __device__ __forceinline__ f4v fzero() { f4v z; z[0]=0.f; z[1]=0.f; z[2]=0.f; z[3]=0.f; return z; }
// fast-rcp transcendentals (v_rcp_f32 ~1ulp; budget is 2e-3 -> fine)
static __device__ __forceinline__ float rcpf(float x) { return __builtin_amdgcn_rcpf(x); }
static __device__ __forceinline__ float sigm(float x) { return rcpf(1.0f + __expf(-x)); }
static __device__ __forceinline__ float tanh2(float x) { return 1.0f - 2.0f * rcpf(1.0f + __expf(2.0f * x)); }

// Fragment-order convert all 8 weight matrices (layout [tile][kc 32][lr 16] of h8v)
// and zero the group flags.
__global__ void conv_w(const float* __restrict__ whh0, const float* __restrict__ wih1,
                       const float* __restrict__ whh1, const float* __restrict__ ow1,
                       const float* __restrict__ ew2,  const float* __restrict__ ew3,
                       const float* __restrict__ hiw,  const float* __restrict__ ciw,
                       f16* __restrict__ dst, int* __restrict__ flags) {
  int i = blockIdx.x * 256 + threadIdx.x;   // 0 .. FRAG_TOTAL-1
  if (blockIdx.x == 0 && threadIdx.x < 128) flags[threadIdx.x] = 0;
  if (i >= FRAG_TOTAL) return;
  const float* src; int base;
  if      (i < 262144)  { src = whh0; base = 0; }
  else if (i < 524288)  { src = wih1; base = 262144; }
  else if (i < 786432)  { src = whh1; base = 524288; }
  else if (i < 819200)  { src = ow1;  base = 786432; }
  else if (i < 884736)  { src = ew2;  base = 819200; }
  else if (i < 950272)  { src = ew3;  base = 884736; }
  else if (i < 1081344) { src = hiw;  base = 950272; }
  else                  { src = ciw;  base = 1081344; }
  int e = i - base;
  int row = e >> 8, col = e & 255;
  int idx = base + ((((row >> 4) << 5) + (col >> 3)) << 7) + ((row & 15) << 3) + (col & 7);
  dst[idx] = (f16)src[e];
}

// group-flag protocol:
//  RELEASE side: __syncthreads() drains each wave's vmcnt(0) before s_barrier
//  (compiler-guaranteed), so all payload stores are complete in the XCD L2 before
//  tid0's RELAXED flag add issues -> no buffer_wbl2, state stays L2-resident.
//  (R10 counters: WRITE_SIZE == state volume with RELEASE = pure wbL2 overhead;
//   FETCH_SIZE tiny = same-XCD reads already hit L2.)
//  ACQUIRE side: unchanged SYSTEM acquire (provides the L1 invalidate needed for
//  the parity-buffer address reuse; empirically does not evict same-XCD L2 lines).
#define RELF(fi)                                                               \
  do { __syncthreads();                                                        \
       if (tid == 0) __hip_atomic_fetch_add(&flg[fi], 1, __ATOMIC_RELAXED,     \
                                            __HIP_MEMORY_SCOPE_SYSTEM);        \
  } while (0)
#define WAITF(fi, tgt)                                                         \
  do { if (tid == 0) {                                                         \
         while (__hip_atomic_load(&flg[fi], __ATOMIC_RELAXED,                  \
                                  __HIP_MEMORY_SCOPE_SYSTEM) < (tgt))          \
           __builtin_amdgcn_s_sleep(2);                                        \
         (void)__hip_atomic_load(&flg[fi], __ATOMIC_ACQUIRE,                   \
                                 __HIP_MEMORY_SCOPE_SYSTEM);                   \
       }                                                                       \
       __syncthreads();                                                        \
  } while (0)

__global__ __launch_bounds__(NTHR, 1)
void traj_kernel(const float* __restrict__ x,
                 const float* __restrict__ ew1, const float* __restrict__ eb1,
                 const float* __restrict__ eb2, const float* __restrict__ eb3,
                 const float* __restrict__ hib, const float* __restrict__ cib,
                 const float* __restrict__ wih0,
                 const float* __restrict__ bih0, const float* __restrict__ bhh0,
                 const float* __restrict__ bih1, const float* __restrict__ bhh1,
                 const float* __restrict__ ob1, const float* __restrict__ ow2,
                 const float* __restrict__ ob2, const float* __restrict__ stok,
                 f16* __restrict__ ws, int* __restrict__ flags,
                 float* __restrict__ out)
{
  __shared__ __align__(16) f16 WL[13 * 4096];    // 104 KB weight tiles
  __shared__ __align__(16) float decsL[512 * 4]; // 8 KB dec stage (f32)
  __shared__ __align__(16) f16 o1s[32 * 136];    // 8.5 KB o1 gather
  __shared__ float w2s[384];
  __shared__ float b0L[64];                      // member-slice L0 biases [G][lr]
  __shared__ float b1L[64];                      // member-slice L1 biases
  __shared__ float wiL[192];                     // member-slice w_ih0 [G][lr][3]
  __shared__ float ob2s[4];

  const int tid  = threadIdx.x;
  const int bid  = blockIdx.x;
  const int g    = (bid & 7) + ((bid >> 7) << 3);   // 0..15
  const int m    = (bid >> 3) & 15;                 // member 0..15
  const int wv   = tid >> 6;
  const int lane = tid & 63;
  const int lr   = lane & 15;
  const int lg   = lane >> 4;

  int* flg = flags + g * 8;
  const int dcol = 16 * m + lr;

  f16* e1g = ws + H0F + g * 131072;
  f16* e2g = ws + H1F + g * 131072;
  f16* e3g = ws + H0F + (16 + g) * 131072;
  f16* o1g = ws + O1F + g * 65536;
  float* decb = (float*)(ws + DECF) + g * 4096;

  // ---- per-lane constants -> LDS (keeps VGPR pressure under the 128 wall) ----
  if (tid < 64) {
    const int G = tid >> 4, l = tid & 15;
    const int gc = G * 256 + 16 * m + l;
    b0L[tid] = bih0[gc] + bhh0[gc];
    b1L[tid] = bih1[gc] + bhh1[gc];
    wiL[tid * 3 + 0] = wih0[gc * 3 + 0];
    wiL[tid * 3 + 1] = wih0[gc * 3 + 1];
    wiL[tid * 3 + 2] = wih0[gc * 3 + 2];
  }
  const float ob1r = ob1[((m & 7) << 4) + lr];
  if (tid < 384) w2s[tid] = ow2[tid];
  if (tid < 3)   ob2s[tid] = ob2[tid];

  auto cptile = [&](int slot, int srcF) {
    ((h8v*)(WL + slot * 4096))[tid] = *(const h8v*)(ws + srcF + tid * 8);
  };
  auto BF = [&](int slot, int k) -> h8v {
    return ((const h8v*)WL)[slot * 512 + ((k << 2) + lg) * 16 + lr];
  };
  auto loadA8 = [&](const f16* gb, int R0, h8v* a) {
    const f16* p0 = gb + (lg >> 1) * 8192 + (size_t)(R0 + lr) * 16 + (lg & 1) * 8;
#pragma unroll
    for (int k = 0; k < 8; ++k) a[k] = *(const h8v*)(p0 + k * 16384);
  };

  // ================= setup: encoder + h/c init (exchange-based) =================
  cptile(0, EW2F + m * 4096);
  cptile(1, EW3F + m * 4096);
  cptile(2, HIWF + m * 4096);
  cptile(3, HIWF + (16 + m) * 4096);
  cptile(4, CIWF + m * 4096);
  cptile(5, CIWF + (16 + m) * 4096);
  __syncthreads();

  { // e1 (VALU)
    const int r = tid;
    float xr[7];
#pragma unroll
    for (int k = 0; k < 7; ++k) xr[k] = x[(size_t)(g * 512 + r) * 7 + k];
    f16 ev[16];
#pragma unroll
    for (int i2 = 0; i2 < 16; ++i2) {
      const int c = 16 * m + i2;
      float a = eb1[c];
#pragma unroll
      for (int k = 0; k < 7; ++k) a += xr[k] * ew1[c * 7 + k];
      ev[i2] = (f16)fmaxf(a, 0.0f);
    }
    *(h8v*)(e1g + m * 8192 + r * 16)     = *(h8v*)&ev[0];
    *(h8v*)(e1g + m * 8192 + r * 16 + 8) = *(h8v*)&ev[8];
  }
  RELF(FE1); WAITF(FE1, 16);

  { // e2 = relu(e1 @ ew2^T)
    const float bb = eb2[dcol];
#pragma unroll
    for (int mt = 0; mt < 4; ++mt) {
      const int R0 = wv * 64 + mt * 16;
      h8v a[8]; loadA8(e1g, R0, a);
      f4v acc = fzero();
#pragma unroll
      for (int k = 0; k < 8; ++k) acc = mfma16(a[k], BF(0, k), acc);
#pragma unroll
      for (int j = 0; j < 4; ++j)
        e2g[m * 8192 + (R0 + 4 * lg + j) * 16 + lr] = (f16)fmaxf(acc[j] + bb, 0.0f);
    }
  }
  RELF(FE2); WAITF(FE2, 16);

  { // e3 = relu(e2 @ ew3^T)
    const float bb = eb3[dcol];
#pragma unroll
    for (int mt = 0; mt < 4; ++mt) {
      const int R0 = wv * 64 + mt * 16;
      h8v a[8]; loadA8(e2g, R0, a);
      f4v acc = fzero();
#pragma unroll
      for (int k = 0; k < 8; ++k) acc = mfma16(a[k], BF(1, k), acc);
#pragma unroll
      for (int j = 0; j < 4; ++j)
        e3g[m * 8192 + (R0 + 4 * lg + j) * 16 + lr] = (f16)fmaxf(acc[j] + bb, 0.0f);
    }
  }
  RELF(FE3); WAITF(FE3, 16);

  // h/c init from e3
  float c0v[4][4], c1v[4][4];
  {
    f16* h0g0 = ws + H0F + g * 131072;   // parity-0 h0
    f16* h1g0 = ws + H1F + g * 131072;   // parity-0 h1
    const float bh0 = hib[dcol], bh1 = hib[256 + dcol];
    const float bc0 = cib[dcol], bc1 = cib[256 + dcol];
#pragma unroll
    for (int mt = 0; mt < 4; ++mt) {
      const int R0 = wv * 64 + mt * 16;
      h8v a[8]; loadA8(e3g, R0, a);
      f4v aH = fzero(), aC = fzero();
#pragma unroll
      for (int k = 0; k < 8; ++k) { aH = mfma16(a[k], BF(2, k), aH); aC = mfma16(a[k], BF(4, k), aC); }
#pragma unroll
      for (int j = 0; j < 4; ++j) {
        h0g0[m * 8192 + (R0 + 4 * lg + j) * 16 + lr] = (f16)(aH[j] + bh0);
        c0v[mt][j] = aC[j] + bc0;
      }
      aH = fzero(); aC = fzero();
#pragma unroll
      for (int k = 0; k < 8; ++k) { aH = mfma16(a[k], BF(3, k), aH); aC = mfma16(a[k], BF(5, k), aC); }
#pragma unroll
      for (int j = 0; j < 4; ++j) {
        h1g0[m * 8192 + (R0 + 4 * lg + j) * 16 + lr] = (f16)(aH[j] + bh1);
        c1v[mt][j] = aC[j] + bc1;
      }
    }
    if (tid < 32) { // dec(0) = start_token (parity 0, f32)
      f4v d; d[0] = stok[0]; d[1] = stok[1]; d[2] = stok[2]; d[3] = 0.f;
      *(f4v*)(decb + (m * 32 + tid) * 4) = d;
    }
  }
  RELF(FDEC);

  // permanent weight tiles
#pragma unroll
  for (int G = 0; G < 4; ++G) {
    cptile(G,     W0F  + (G * 16 + m) * 4096);
    cptile(4 + G, W1IF + (G * 16 + m) * 4096);
    cptile(8 + G, W1HF + (G * 16 + m) * 4096);
  }
  cptile(12, OW1F + (m & 7) * 4096);
  __syncthreads();

  // ---- prologue: all init state visible; precompute g0(0) = h0(0) @ W0 ----
  f4v g0a[4][4];
  WAITF(FDEC, 16);
  {
    const f16* h0old0 = ws + H0F + g * 131072;   // parity 0
#pragma unroll
    for (int mt = 0; mt < 4; ++mt) {
      const int R0 = wv * 64 + mt * 16;
      h8v a[8]; loadA8(h0old0, R0, a);
#pragma unroll
      for (int G = 0; G < 4; ++G) g0a[mt][G] = fzero();
#pragma unroll
      for (int k = 0; k < 8; ++k) {
        g0a[mt][0] = mfma16(a[k], BF(0, k), g0a[mt][0]);
        g0a[mt][1] = mfma16(a[k], BF(1, k), g0a[mt][1]);
        g0a[mt][2] = mfma16(a[k], BF(2, k), g0a[mt][2]);
        g0a[mt][3] = mfma16(a[k], BF(3, k), g0a[mt][3]);
      }
    }
  }

  // ================= T = 200 sequential decoder steps =================
  // Sync-cover schedule:
  //   FDEC <- g0 mt3 (tail) ; FH0 <- Phh mt0,1 ; FH1 <- g0 mt0,1 ; FO1 <- g0 mt2.
#pragma unroll 1
  for (int t = 0; t < TT; ++t) {
    const int p = t & 1;
    f16* h0new = ws + H0F + ((p ^ 1) * 16 + g) * 131072;
    f16* h1old = ws + H1F + (p * 16 + g) * 131072;
    f16* h1new = ws + H1F + ((p ^ 1) * 16 + g) * 131072;
    const float* decp = decb + p * 2048;
    float* decn = decb + (p ^ 1) * 2048;

    // (A) dec ready (covered by g0 mt3 of previous iteration)
    WAITF(FDEC, 16 * (t + 1));
    *(f4v*)(decsL + tid * 4) = *(const f4v*)(decp + tid * 4);
    __syncthreads();

    // (B) E0: consume g0a + dec -> h0new
    {
      float cb0[4], cw[4][3];
#pragma unroll
      for (int G = 0; G < 4; ++G) {
        cb0[G]   = b0L[G * 16 + lr];
        cw[G][0] = wiL[(G * 16 + lr) * 3 + 0];
        cw[G][1] = wiL[(G * 16 + lr) * 3 + 1];
        cw[G][2] = wiL[(G * 16 + lr) * 3 + 2];
      }
#pragma unroll
      for (int mt = 0; mt < 4; ++mt) {
        const int R0 = wv * 64 + mt * 16;
#pragma unroll
        for (int j = 0; j < 4; ++j) {
          const int row = R0 + 4 * lg + j;
          f4v d4 = *(const f4v*)(decsL + row * 4);
          float gi = g0a[mt][0][j] + cb0[0] + d4[0]*cw[0][0] + d4[1]*cw[0][1] + d4[2]*cw[0][2];
          float gf = g0a[mt][1][j] + cb0[1] + d4[0]*cw[1][0] + d4[1]*cw[1][1] + d4[2]*cw[1][2];
          float gg = g0a[mt][2][j] + cb0[2] + d4[0]*cw[2][0] + d4[1]*cw[2][1] + d4[2]*cw[2][2];
          float go = g0a[mt][3][j] + cb0[3] + d4[0]*cw[3][0] + d4[1]*cw[3][1] + d4[2]*cw[3][2];
          float cn = sigm(gf) * c0v[mt][j] + sigm(gi) * tanh2(gg);
          c0v[mt][j] = cn;
          h0new[m * 8192 + row * 16 + lr] = (f16)(sigm(go) * tanh2(cn));
        }
      }
    }
    RELF(FH0);

    // (C) Phh mt0,1 = h1old @ W1h : covers the FH0 wait
    f4v ph[2][4];
#pragma unroll
    for (int mt = 0; mt < 2; ++mt) {
      const int R0 = wv * 64 + mt * 16;
      h8v a[8]; loadA8(h1old, R0, a);
#pragma unroll
      for (int G = 0; G < 4; ++G) ph[mt][G] = fzero();
#pragma unroll
      for (int k = 0; k < 8; ++k) {
        ph[mt][0] = mfma16(a[k], BF(8,  k), ph[mt][0]);
        ph[mt][1] = mfma16(a[k], BF(9,  k), ph[mt][1]);
        ph[mt][2] = mfma16(a[k], BF(10, k), ph[mt][2]);
        ph[mt][3] = mfma16(a[k], BF(11, k), ph[mt][3]);
      }
    }
    WAITF(FH0, 16 * (t + 1));

    // (D) L1
    {
      float cb1[4];
#pragma unroll
      for (int G = 0; G < 4; ++G) cb1[G] = b1L[G * 16 + lr];
      // mt 0,1: += W1i, then elementwise
#pragma unroll
      for (int mt = 0; mt < 2; ++mt) {
        const int R0 = wv * 64 + mt * 16;
        h8v a[8]; loadA8(h0new, R0, a);
#pragma unroll
        for (int k = 0; k < 8; ++k) {
          ph[mt][0] = mfma16(a[k], BF(4, k), ph[mt][0]);
          ph[mt][1] = mfma16(a[k], BF(5, k), ph[mt][1]);
          ph[mt][2] = mfma16(a[k], BF(6, k), ph[mt][2]);
          ph[mt][3] = mfma16(a[k], BF(7, k), ph[mt][3]);
        }
#pragma unroll
        for (int j = 0; j < 4; ++j) {
          const int row = R0 + 4 * lg + j;
          float cn = sigm(ph[mt][1][j] + cb1[1]) * c1v[mt][j]
                   + sigm(ph[mt][0][j] + cb1[0]) * tanh2(ph[mt][2][j] + cb1[2]);
          c1v[mt][j] = cn;
          h1new[m * 8192 + row * 16 + lr] = (f16)(sigm(ph[mt][3][j] + cb1[3]) * tanh2(cn));
        }
      }
      // mt 2,3: fresh accumulators, W1h + W1i
#pragma unroll
      for (int mt = 2; mt < 4; ++mt) {
        const int R0 = wv * 64 + mt * 16;
        f4v ai = fzero(), af = fzero(), ag = fzero(), ao = fzero();
        {
          h8v a[8]; loadA8(h1old, R0, a);
#pragma unroll
          for (int k = 0; k < 8; ++k) {
            ai = mfma16(a[k], BF(8,  k), ai);
            af = mfma16(a[k], BF(9,  k), af);
            ag = mfma16(a[k], BF(10, k), ag);
            ao = mfma16(a[k], BF(11, k), ao);
          }
        }
        {
          h8v a[8]; loadA8(h0new, R0, a);
#pragma unroll
          for (int k = 0; k < 8; ++k) {
            ai = mfma16(a[k], BF(4, k), ai);
            af = mfma16(a[k], BF(5, k), af);
            ag = mfma16(a[k], BF(6, k), ag);
            ao = mfma16(a[k], BF(7, k), ao);
          }
        }
#pragma unroll
        for (int j = 0; j < 4; ++j) {
          const int row = R0 + 4 * lg + j;
          float cn = sigm(af[j] + cb1[1]) * c1v[mt][j]
                   + sigm(ai[j] + cb1[0]) * tanh2(ag[j] + cb1[2]);
          c1v[mt][j] = cn;
          h1new[m * 8192 + row * 16 + lr] = (f16)(sigm(ao[j] + cb1[3]) * tanh2(cn));
        }
      }
    }
    RELF(FH1);

    // (E) g0(t+1) mt0,1 = h0new @ W0 : covers the FH1 wait
#pragma unroll
    for (int mt = 0; mt < 2; ++mt) {
      const int R0 = wv * 64 + mt * 16;
      h8v a[8]; loadA8(h0new, R0, a);
#pragma unroll
      for (int G = 0; G < 4; ++G) g0a[mt][G] = fzero();
#pragma unroll
      for (int k = 0; k < 8; ++k) {
        g0a[mt][0] = mfma16(a[k], BF(0, k), g0a[mt][0]);
        g0a[mt][1] = mfma16(a[k], BF(1, k), g0a[mt][1]);
        g0a[mt][2] = mfma16(a[k], BF(2, k), g0a[mt][2]);
        g0a[mt][3] = mfma16(a[k], BF(3, k), g0a[mt][3]);
      }
    }
    WAITF(FH1, 16 * (t + 1));

    // (F) head: o1 = relu(h1new @ ow1^T); pair (m, m+8) splits rows
    {
      const int Rh = ((m >> 3) << 8) + wv * 32;
#pragma unroll
      for (int mt2 = 0; mt2 < 2; ++mt2) {
        const int R0 = Rh + mt2 * 16;
        h8v a[8]; loadA8(h1new, R0, a);
        f4v acc = fzero();
#pragma unroll
        for (int k = 0; k < 8; ++k) acc = mfma16(a[k], BF(12, k), acc);
#pragma unroll
        for (int j = 0; j < 4; ++j)
          o1g[(m & 7) * 8192 + (R0 + 4 * lg + j) * 16 + lr] =
              (f16)fmaxf(acc[j] + ob1r, 0.0f);
      }
    }
    RELF(FO1);

    // (G) g0(t+1) mt2 : covers the FO1 wait
    {
      const int R0 = wv * 64 + 2 * 16;
      h8v a[8]; loadA8(h0new, R0, a);
#pragma unroll
      for (int G = 0; G < 4; ++G) g0a[2][G] = fzero();
#pragma unroll
      for (int k = 0; k < 8; ++k) {
        g0a[2][0] = mfma16(a[k], BF(0, k), g0a[2][0]);
        g0a[2][1] = mfma16(a[k], BF(1, k), g0a[2][1]);
        g0a[2][2] = mfma16(a[k], BF(2, k), g0a[2][2]);
        g0a[2][3] = mfma16(a[k], BF(3, k), g0a[2][3]);
      }
    }
    WAITF(FO1, 16 * (t + 1));

    // (H) final: out = relu-o1 @ out_w2^T + b2 for member's 32 rows; feed dec
    {
      const int r32 = tid >> 4, t8 = (tid & 15) >> 1, hf = tid & 1;
      *(h8v*)(o1s + r32 * 136 + t8 * 16 + hf * 8) =
          *(const h8v*)(o1g + t8 * 8192 + (m * 32 + r32) * 16 + hf * 8);
    }
    __syncthreads();
    {
      const int r = tid >> 4, jj = tid & 15;
      float a0 = 0.f, a1 = 0.f, a2 = 0.f;
#pragma unroll
      for (int kk = 0; kk < 8; ++kk) {
        const int k = jj * 8 + kk;
        const float ov = (float)o1s[r * 136 + k];
        a0 += ov * w2s[k];
        a1 += ov * w2s[128 + k];
        a2 += ov * w2s[256 + k];
      }
#pragma unroll
      for (int s = 8; s >= 1; s >>= 1) {
        a0 += __shfl_xor(a0, s);
        a1 += __shfl_xor(a1, s);
        a2 += __shfl_xor(a2, s);
      }
      if (jj == 0) {
        a0 += ob2s[0]; a1 += ob2s[1]; a2 += ob2s[2];
        float* op = out + ((size_t)(g * 512 + m * 32 + r) * TT + t) * 3;
        op[0] = a0; op[1] = a1; op[2] = a2;
        f4v d; d[0] = a0; d[1] = a1; d[2] = a2; d[3] = 0.f;
        *(f4v*)(decn + (m * 32 + r) * 4) = d;
      }
    }
    RELF(FDEC);

    // (I) g0(t+1) mt3 : covers the next iteration's FDEC wait
    {
      const int R0 = wv * 64 + 3 * 16;
      h8v a[8]; loadA8(h0new, R0, a);
#pragma unroll
      for (int G = 0; G < 4; ++G) g0a[3][G] = fzero();
#pragma unroll
      for (int k = 0; k < 8; ++k) {
        g0a[3][0] = mfma16(a[k], BF(0, k), g0a[3][0]);
        g0a[3][1] = mfma16(a[k], BF(1, k), g0a[3][1]);
        g0a[3][2] = mfma16(a[k], BF(2, k), g0a[3][2]);
        g0a[3][3] = mfma16(a[k], BF(3, k), g0a[3][3]);
      }
    }
  }
}

extern "C" void kernel_launch(void* const* d_in, const int* in_sizes, int n_in,
                              void* d_out, int out_size, void* d_ws, size_t ws_size,
                              hipStream_t stream) {
  (void)in_sizes; (void)n_in; (void)out_size; (void)ws_size;
  f16* wk = (f16*)d_ws;
  int* flags = (int*)((char*)d_ws + (size_t)FLGF * 2);
  conv_w<<<(FRAG_TOTAL + 255) / 256, 256, 0, stream>>>(
      (const float*)d_in[12], (const float*)d_in[15],
      (const float*)d_in[16], (const float*)d_in[19],
      (const float*)d_in[3],  (const float*)d_in[5],
      (const float*)d_in[7],  (const float*)d_in[9],
      wk, flags);
  traj_kernel<<<NWG, NTHR, 0, stream>>>(
      (const float*)d_in[0],
      (const float*)d_in[1],  (const float*)d_in[2],
      (const float*)d_in[4],  (const float*)d_in[6],
      (const float*)d_in[8],  (const float*)d_in[10],
      (const float*)d_in[11],
      (const float*)d_in[13], (const float*)d_in[14],
      (const float*)d_in[17], (const float*)d_in[18],
      (const float*)d_in[20], (const float*)d_in[21],
      (const float*)d_in[22], (const float*)d_in[23],
      wk, flags, (float*)d_out);
}